// Round 1
// baseline (93.280 us; speedup 1.0000x reference)
//
#include <hip/hip_runtime.h>

#define Bb   8
#define Nn   4096
#define Hh   11
#define Wdd  176
#define HW   (Hh * Wdd)      // 1936
#define CIN  72
#define COUT 18
#define WINN 5
#define NSAMP (Bb * Nn * WINN * WINN)        // 819200
#define M_PER_B (Nn * WINN * WINN * 6)       // 614400

// Kernel 1: 1x1 conv 72 -> 18. One thread per (b, o, hw).
__global__ __launch_bounds__(256) void conv1x1_kernel(
    const float* __restrict__ feat,   // [B,72,HW]
    const float* __restrict__ Wc,     // [18,72]
    const float* __restrict__ bc,     // [18]
    float* __restrict__ out)          // [B,18,HW]
{
    int tid = blockIdx.x * blockDim.x + threadIdx.x;
    const int total = Bb * COUT * HW;
    if (tid >= total) return;
    int hw = tid % HW;
    int o  = (tid / HW) % COUT;
    int b  = tid / (HW * COUT);
    const float* fb = feat + (size_t)b * CIN * HW + hw;
    const float* w  = Wc + o * CIN;
    float acc = bc[o];
#pragma unroll 8
    for (int c = 0; c < CIN; ++c)
        acc = fmaf(fb[(size_t)c * HW], w[c], acc);
    out[tid] = acc;
}

// Kernel 2: box geometry + nearest grid-sample gather + 6x 4-class CE, reduce.
__global__ __launch_bounds__(256) void roi_ce_kernel(
    const float* __restrict__ rois,    // [B,N,7]
    const float* __restrict__ feat18,  // [B,18,HW] (ws)
    const float* __restrict__ labels,  // [B,6,HW]
    float* __restrict__ out)           // [1]
{
    float local = 0.0f;
    const int stride = gridDim.x * blockDim.x;
    for (int p = blockIdx.x * blockDim.x + threadIdx.x; p < NSAMP; p += stride) {
        int j = p % WINN;                 // indexes gx / ih (height axis)
        int i = (p / WINN) % WINN;        // indexes gz / iw (width axis)
        int n = (p / (WINN * WINN)) % Nn;
        int b = p / (WINN * WINN * Nn);

        const float* r = rois + ((size_t)b * Nn + n) * 7;
        float x0 = r[0], z0 = r[2], dx = r[3], dy = r[4], dz = r[5], th = r[6];
        float half = (dy * cosf(th) + dx * sinf(th)) * 0.5f;
        float x1 = x0 - half, x2 = x0 + half;
        float z1 = z0 - dz * 0.5f, z2 = z0 + dz * 0.5f;

        float gz = z1 + (z2 - z1) * ((float)i * 0.25f);
        float gx = x1 + (x2 - x1) * ((float)j * 0.25f);
        float gzn = (gz - 1.0f) * 0.25f;        // /4 exact
        float gxn = (gx - 35.2f) / 70.4f;

        int iw = (int)rintf((gzn + 1.0f) * 0.5f * (float)(Wdd - 1)); // ties-to-even, matches jnp.rint
        int ih = (int)rintf((gxn + 1.0f) * 0.5f * (float)(Hh - 1));
        bool valid = (iw >= 0) && (iw < Wdd) && (ih >= 0) && (ih < Hh);
        int iwc = min(max(iw, 0), Wdd - 1);
        int ihc = min(max(ih, 0), Hh - 1);
        int idx = ihc * Wdd + iwc;

        const float* fb = feat18 + (size_t)b * COUT * HW + idx;
        const float* gb = labels + (size_t)b * 6 * HW + idx;
        float vm = valid ? 1.0f : 0.0f;

#pragma unroll
        for (int g = 0; g < 6; ++g) {
            float f0 = fb[(3 * g + 0) * HW] * vm;
            float f1 = fb[(3 * g + 1) * HW] * vm;
            float f2 = fb[(3 * g + 2) * HW] * vm;
            float gv = gb[g * HW] * vm;
            int t = (int)gv;
            if (t < 0) t = 0;                   // sg * (sg >= 0)
            // logits = [0, f0, f1, f2]; nll = lse - logits[t]
            float m = fmaxf(fmaxf(f0, f1), fmaxf(f2, 0.0f));
            float s = __expf(0.0f - m) + __expf(f0 - m) + __expf(f1 - m) + __expf(f2 - m);
            float lse = m + __logf(s);
            float lt = (t == 0) ? 0.0f : (t == 1 ? f0 : (t == 2 ? f1 : f2));
            local += lse - lt;
        }
    }

    // wave reduction (64 lanes)
    for (int off = 32; off > 0; off >>= 1)
        local += __shfl_down(local, off, 64);
    __shared__ float wsum[4];
    int lane = threadIdx.x & 63;
    int wid  = threadIdx.x >> 6;
    if (lane == 0) wsum[wid] = local;
    __syncthreads();
    if (threadIdx.x == 0) {
        float s = wsum[0] + wsum[1] + wsum[2] + wsum[3];
        atomicAdd(out, s * (1.0f / (float)M_PER_B));
    }
}

extern "C" void kernel_launch(void* const* d_in, const int* in_sizes, int n_in,
                              void* d_out, int out_size, void* d_ws, size_t ws_size,
                              hipStream_t stream) {
    const float* rois   = (const float*)d_in[0];  // [8,4096,7]
    const float* feat   = (const float*)d_in[1];  // [8,72,11,176]
    const float* labels = (const float*)d_in[2];  // [8,6*11*176]
    const float* Wc     = (const float*)d_in[3];  // [18,72]
    const float* bc     = (const float*)d_in[4];  // [18]
    float* out = (float*)d_out;                   // [1]
    float* feat18 = (float*)d_ws;                 // [8,18,1936] = 1.1 MB

    hipMemsetAsync(out, 0, sizeof(float) * out_size, stream);

    const int conv_total = Bb * COUT * HW;        // 278784
    conv1x1_kernel<<<(conv_total + 255) / 256, 256, 0, stream>>>(feat, Wc, bc, feat18);

    roi_ce_kernel<<<400, 256, 0, stream>>>(rois, feat18, labels, out);
}

// Round 2
// 82.795 us; speedup vs baseline: 1.1266x; 1.1266x over previous
//
#include <hip/hip_runtime.h>

#define Bb   8
#define Nn   4096
#define Hh   11
#define Wdd  176
#define HW   (Hh * Wdd)      // 1936
#define CIN  72
#define COUT 18
#define WINN 5
#define NCELL (Bb * HW)                      // 15488
#define NBOX  (Bb * Nn)                      // 32768
#define M_PER_B (Nn * WINN * WINN * 6)       // 614400
#define C6LN4 8.317766166719343f             // 6 * ln(4), invalid-sample CE

// Kernel 1: fused 1x1 conv (72->18) + 6x 4-class CE per spatial cell.
// One thread per (b, hw). Writes CEsum[b*HW+hw] = sum over 6 groups of nll.
__global__ __launch_bounds__(256) void conv_ce_kernel(
    const float* __restrict__ feat,   // [B,72,HW]
    const float* __restrict__ labels, // [B,6,HW]
    const float* __restrict__ Wc,     // [18,72]
    const float* __restrict__ bc,     // [18]
    float* __restrict__ cesum)        // [B*HW]
{
    __shared__ float sW[COUT * CIN];
    __shared__ float sB[COUT];
    for (int i = threadIdx.x; i < COUT * CIN; i += 256) sW[i] = Wc[i];
    if (threadIdx.x < COUT) sB[threadIdx.x] = bc[threadIdx.x];
    __syncthreads();

    int tid = blockIdx.x * 256 + threadIdx.x;
    if (tid >= NCELL) return;
    int hw = tid % HW;
    int b  = tid / HW;

    const float* fb = feat + (size_t)b * CIN * HW + hw;
    float acc[COUT];
#pragma unroll
    for (int o = 0; o < COUT; ++o) acc[o] = sB[o];
    for (int c = 0; c < CIN; ++c) {
        float f = fb[(size_t)c * HW];      // coalesced across lanes (consecutive hw)
#pragma unroll
        for (int o = 0; o < COUT; ++o)
            acc[o] = fmaf(f, sW[o * CIN + c], acc[o]);   // sW: wave-uniform -> LDS broadcast, free
    }

    const float* gb = labels + (size_t)b * 6 * HW + hw;
    float s = 0.0f;
#pragma unroll
    for (int g = 0; g < 6; ++g) {
        float f0 = acc[3 * g + 0], f1 = acc[3 * g + 1], f2 = acc[3 * g + 2];
        int t = (int)gb[(size_t)g * HW];   // labels in {0..3}, nonneg
        float m = fmaxf(fmaxf(f0, f1), fmaxf(f2, 0.0f));
        float sum = __expf(0.0f - m) + __expf(f0 - m) + __expf(f1 - m) + __expf(f2 - m);
        float lse = m + __logf(sum);
        float lt = (t == 0) ? 0.0f : ((t == 1) ? f0 : ((t == 2) ? f1 : f2));
        s += lse - lt;
    }
    cesum[tid] = s;
}

// Kernel 2: one thread per box. Box math once, 25 single-float gathers of the
// per-cell CE table (62 KB, L1/L2 resident), invalid -> constant 6*ln4.
__global__ __launch_bounds__(256) void box_ce_reduce_kernel(
    const float* __restrict__ rois,   // [B,N,7]
    const float* __restrict__ cesum,  // [B*HW]
    float* __restrict__ out)          // [1]
{
    int tid = blockIdx.x * 256 + threadIdx.x;   // 0..NBOX-1 (exact grid)
    float local = 0.0f;

    int b = tid >> 12;                          // tid / 4096
    const float* r = rois + (size_t)tid * 7;
    float x0 = r[0], z0 = r[2], dx = r[3], dy = r[4], dz = r[5], th = r[6];
    float half = (dy * cosf(th) + dx * sinf(th)) * 0.5f;
    float x1 = x0 - half, x2 = x0 + half;
    float z1 = z0 - dz * 0.5f, z2 = z0 + dz * 0.5f;

    int   iw[5], ih[5];
    bool  vw[5], vh[5];
#pragma unroll
    for (int k = 0; k < 5; ++k) {
        float t = (float)k * 0.25f;
        float gz  = z1 + (z2 - z1) * t;
        float gzn = (gz - 1.0f) * 0.25f;
        int w = (int)rintf((gzn + 1.0f) * 0.5f * (float)(Wdd - 1));
        vw[k] = (w >= 0) && (w < Wdd);
        iw[k] = min(max(w, 0), Wdd - 1);
        float gx  = x1 + (x2 - x1) * t;
        float gxn = (gx - 35.2f) / 70.4f;
        int h = (int)rintf((gxn + 1.0f) * 0.5f * (float)(Hh - 1));
        vh[k] = (h >= 0) && (h < Hh);
        ih[k] = min(max(h, 0), Hh - 1);
    }

    const float* cb = cesum + (size_t)b * HW;
#pragma unroll
    for (int j = 0; j < 5; ++j) {
#pragma unroll
        for (int i = 0; i < 5; ++i) {
            local += (vh[j] && vw[i]) ? cb[ih[j] * Wdd + iw[i]] : C6LN4;
        }
    }

    // wave (64-lane) + block reduction, one atomic per block
    for (int off = 32; off > 0; off >>= 1)
        local += __shfl_down(local, off, 64);
    __shared__ float wsum[4];
    int lane = threadIdx.x & 63;
    int wid  = threadIdx.x >> 6;
    if (lane == 0) wsum[wid] = local;
    __syncthreads();
    if (threadIdx.x == 0) {
        float s = wsum[0] + wsum[1] + wsum[2] + wsum[3];
        atomicAdd(out, s * (1.0f / (float)M_PER_B));
    }
}

extern "C" void kernel_launch(void* const* d_in, const int* in_sizes, int n_in,
                              void* d_out, int out_size, void* d_ws, size_t ws_size,
                              hipStream_t stream) {
    const float* rois   = (const float*)d_in[0];  // [8,4096,7]
    const float* feat   = (const float*)d_in[1];  // [8,72,11,176]
    const float* labels = (const float*)d_in[2];  // [8,6*11*176]
    const float* Wc     = (const float*)d_in[3];  // [18,72]
    const float* bc     = (const float*)d_in[4];  // [18]
    float* out   = (float*)d_out;                 // [1]
    float* cesum = (float*)d_ws;                  // [15488] = 62 KB

    hipMemsetAsync(out, 0, sizeof(float) * out_size, stream);

    conv_ce_kernel<<<(NCELL + 255) / 256, 256, 0, stream>>>(feat, labels, Wc, bc, cesum);
    box_ce_reduce_kernel<<<NBOX / 256, 256, 0, stream>>>(rois, cesum, out);
}